// Round 7
// baseline (341.921 us; speedup 1.0000x reference)
//
#include <hip/hip_runtime.h>
#include <cstdint>
#include <cstddef>

typedef __attribute__((ext_vector_type(8))) short bf16x8;
typedef __attribute__((ext_vector_type(4))) float f32x4;
typedef __attribute__((ext_vector_type(4))) int i32x4;

__device__ inline unsigned short cvt_bf16_rne(float f) {
    unsigned u = __builtin_bit_cast(unsigned, f);
    u = (u + 0x7FFFu + ((u >> 16) & 1u)) >> 16;
    return (unsigned short)u;
}
__device__ inline float bf16_to_f32(unsigned short s) {
    return __builtin_bit_cast(float, (unsigned)s << 16);
}

// XCD-aware bijective swizzle for 1024-block conv grids (1024 % 8 == 0):
// hardware round-robins dispatch index lin across XCDs; remap so each XCD
// owns a contiguous 128-tile chunk (one action's half -> its apack slice and
// halo rows stay in that XCD's private L2).
__device__ __forceinline__ int xcd_swz1024(int lin) {
    return (lin & 7) * 128 + (lin >> 3);
}

// ---------------------------------------------------------------------------
// Pack mid-layer weights (layers 1..3) into MFMA A-fragment lane order (bf16).
// grid dim3(9, 4, 3) [tap, action, layer], 512 threads.
// Block (0,0,0) also clears the mask-format flag (detect runs in a LATER
// kernel -> stream order guarantees the clear lands first).
__global__ void apack_all_kernel(const float* __restrict__ cw1,
                                 const float* __restrict__ cw2,
                                 const float* __restrict__ cw3,
                                 char* __restrict__ apack,
                                 int* __restrict__ flag) {
    int t = threadIdx.x;
    int tap = blockIdx.x, a = blockIdx.y, lz = blockIdx.z;
    if (tap == 0 && a == 0 && lz == 0 && t == 0) *flag = 0;
    const float* cw = (lz == 0) ? cw1 : (lz == 1 ? cw2 : cw3);
    char* outp = apack + (size_t)lz * 294912;
    int ks = t >> 8, mf = (t >> 6) & 3, lane = t & 63;
    int n = lane & 15, q = lane >> 4;
    int co = mf * 16 + n;
    int ci0 = ks * 32 + q * 8;
    unsigned d[4];
    #pragma unroll
    for (int jj = 0; jj < 4; ++jj) {
        unsigned short h0 = cvt_bf16_rne(cw[((size_t)(a * 64 + co) * 64 + ci0 + 2 * jj + 0) * 9 + tap]);
        unsigned short h1 = cvt_bf16_rne(cw[((size_t)(a * 64 + co) * 64 + ci0 + 2 * jj + 1) * 9 + tap]);
        d[jj] = (unsigned)h0 | ((unsigned)h1 << 16);
    }
    *(i32x4*)(outp + ((((size_t)(a * 9 + tap) * 2 + ks) * 4 + mf) * 1024 + lane * 16)) =
        *(i32x4*)d;
}

// ---------------------------------------------------------------------------
// Shared MFMA main loop for the mid layers: consumes the staged 10x34 halo
// tile in lds4, runs the 64->64 implicit GEMM into acc (bias pre-loaded).
__device__ __forceinline__ void conv_mid_mainloop(const i32x4* lds4,
                                                  const char* __restrict__ apack_l,
                                                  const float* __restrict__ cb,
                                                  f32x4 acc[4][4],
                                                  int a, int tid) {
    int lane = tid & 63, wv = tid >> 6;
    int n = lane & 15, q = lane >> 4;

    #pragma unroll
    for (int mf = 0; mf < 4; ++mf) {
        f32x4 bb = *(const f32x4*)(cb + a * 64 + mf * 16 + q * 4);
        #pragma unroll
        for (int nf = 0; nf < 4; ++nf) acc[mf][nf] = bb;
    }

    int base_nf[4];
    #pragma unroll
    for (int nf = 0; nf < 4; ++nf) {
        int orl = wv * 2 + (nf >> 1);
        int ocl = ((nf & 1) << 4) + n;
        base_nf[nf] = (orl * 34 + ocl) * 9 + q;  // i32x4 index at ty=tx=0,ks=0
    }
    const char* ap = apack_l + (size_t)a * 9 * 8192 + lane * 16;

    #pragma unroll
    for (int tap = 0; tap < 9; ++tap) {
        const int ty = tap / 3, tx = tap - ty * 3;
        const int toff = (ty * 34 + tx) * 9;
        #pragma unroll
        for (int ks = 0; ks < 2; ++ks) {
            bf16x8 Af[4], Bf[4];
            #pragma unroll
            for (int mf = 0; mf < 4; ++mf)
                Af[mf] = __builtin_bit_cast(bf16x8,
                    *(const i32x4*)(ap + (((tap * 2 + ks) * 4 + mf) << 10)));
            #pragma unroll
            for (int nf = 0; nf < 4; ++nf)
                Bf[nf] = __builtin_bit_cast(bf16x8, lds4[base_nf[nf] + toff + ks * 4]);
            #pragma unroll
            for (int mf = 0; mf < 4; ++mf)
                #pragma unroll
                for (int nf = 0; nf < 4; ++nf)
                    acc[mf][nf] = __builtin_amdgcn_mfma_f32_16x16x32_bf16(
                        Af[mf], Bf[nf], acc[mf][nf], 0, 0, 0);
        }
    }
}

// Standard epilogue: ReLU + bf16 pack + store act tile.
__device__ __forceinline__ void conv_mid_store(f32x4 acc[4][4],
                                               unsigned short* __restrict__ act_out,
                                               int a, int r0, int c0, int tid) {
    int lane = tid & 63, wv = tid >> 6;
    int n = lane & 15, q = lane >> 4;
    #pragma unroll
    for (int nf = 0; nf < 4; ++nf) {
        int grow = r0 + wv * 2 + (nf >> 1);
        int gcol = c0 + ((nf & 1) << 4) + n;
        char* ob = (char*)act_out + (((size_t)(a << 16) + (grow << 8) + gcol) << 7) + q * 8;
        #pragma unroll
        for (int mf = 0; mf < 4; ++mf) {
            f32x4 v = acc[mf][nf];
            unsigned d0 = (unsigned)cvt_bf16_rne(fmaxf(v.x, 0.0f))
                        | ((unsigned)cvt_bf16_rne(fmaxf(v.y, 0.0f)) << 16);
            unsigned d1 = (unsigned)cvt_bf16_rne(fmaxf(v.z, 0.0f))
                        | ((unsigned)cvt_bf16_rne(fmaxf(v.w, 0.0f)) << 16);
            uint2 st; st.x = d0; st.y = d1;
            *(uint2*)(ob + mf * 32) = st;
        }
    }
}

// Halo staging from a bf16 act buffer.
__device__ __forceinline__ void conv_mid_stage(i32x4* lds4,
                                               const char* __restrict__ actb,
                                               int a, int r0, int c0, int tid) {
    for (int s = tid; s < 2720; s += 256) {
        int px = s >> 3, o = s & 7;
        int prow = px / 34, pcol = px - prow * 34;
        int grow = r0 - 1 + prow, gcol = c0 - 1 + pcol;
        i32x4 v = {0, 0, 0, 0};
        if ((unsigned)grow < 256u && (unsigned)gcol < 256u)
            v = *(const i32x4*)(actb + (((size_t)(a << 16) + (grow << 8) + gcol) << 7) + (o << 4));
        lds4[px * 9 + o] = v;
    }
}

// ---------------------------------------------------------------------------
// Mid layers 2,3: stage bf16 act tile from global, MFMA, store act tile.
// grid dim3(8, 32, 4), 256 threads, XCD-swizzled.
__global__ __launch_bounds__(256, 3)
void conv_mid_mfma(const unsigned short* __restrict__ act_in,
                   const char* __restrict__ apack_l,
                   const float* __restrict__ cb,
                   unsigned short* __restrict__ act_out) {
    __shared__ i32x4 lds4[340 * 9];
    int tid = threadIdx.x;
    int lin = blockIdx.x + (blockIdx.y << 3) + (blockIdx.z << 8);
    int wg = xcd_swz1024(lin);
    int a = wg >> 8;
    int r0 = ((wg >> 3) & 31) * 8, c0 = (wg & 7) * 32;
    conv_mid_stage(lds4, (const char*)act_in, a, r0, c0, tid);
    __syncthreads();
    f32x4 acc[4][4];
    conv_mid_mainloop(lds4, apack_l, cb, acc, a, tid);
    conv_mid_store(acc, act_out, a, r0, c0, tid);
}

// ---------------------------------------------------------------------------
// Layer 1 with layer 0 fused (z<4), plus the mask-format detect folded into
// the spare z==4 slice (flag was cleared by the preceding apack launch).
// grid dim3(8, 32, 5), 256 threads.
__global__ __launch_bounds__(256, 3)
void conv_mid_fused0(const float* __restrict__ img,
                     const float* __restrict__ cw0,
                     const float* __restrict__ cb0,
                     const char* __restrict__ apack_l,
                     const float* __restrict__ cb,
                     unsigned short* __restrict__ act_out,
                     const unsigned int* __restrict__ mask_u32,
                     int* __restrict__ flag) {
    __shared__ i32x4 lds4[340 * 9];
    __shared__ float img_s[12 * 36];
    int tid = threadIdx.x;

    if (blockIdx.z == 4) {
        // detect x_mask storage: 0 = int32 {0,1}, 1 = bytes, 2 = float32
        if (blockIdx.y < 4) {
            int i = ((blockIdx.y * 8 + blockIdx.x) * 256 + tid);
            int f = 0;
            #pragma unroll
            for (int k = 0; k < 4; ++k) {
                unsigned int v = mask_u32[i * 4 + k];
                if (v == 0x3F800000u) f |= 2;
                else if (v > 1u) f |= 1;
            }
            if (f) atomicOr(flag, f);
        }
        return;
    }

    int lin = blockIdx.x + (blockIdx.y << 3) + (blockIdx.z << 8);
    int wg = xcd_swz1024(lin);
    int a = wg >> 8;
    int r0 = ((wg >> 3) & 31) * 8, c0 = (wg & 7) * 32;

    for (int s = tid; s < 432; s += 256) {
        int ir = s / 36, ic = s - ir * 36;
        int gr = r0 - 2 + ir, gc = c0 - 2 + ic;
        img_s[s] = ((unsigned)gr < 256u && (unsigned)gc < 256u) ? img[gr * 256 + gc] : 0.0f;
    }
    __syncthreads();

    int o = tid & 7;
    float wr[8][9], br[8];
    #pragma unroll
    for (int j = 0; j < 8; ++j) {
        const float* wp = cw0 + ((size_t)a * 64 + o * 8 + j) * 9;
        #pragma unroll
        for (int t = 0; t < 9; ++t) wr[j][t] = wp[t];
        br[j] = cb0[a * 64 + o * 8 + j];
    }

    for (int s = tid; s < 2720; s += 256) {
        int px = s >> 3;
        int prow = px / 34, pcol = px - prow * 34;
        int grow = r0 - 1 + prow, gcol = c0 - 1 + pcol;
        i32x4 v = {0, 0, 0, 0};
        if ((unsigned)grow < 256u && (unsigned)gcol < 256u) {
            float accv[8];
            #pragma unroll
            for (int j = 0; j < 8; ++j) accv[j] = br[j];
            #pragma unroll
            for (int dy = 0; dy < 3; ++dy)
                #pragma unroll
                for (int dx = 0; dx < 3; ++dx) {
                    float iv = img_s[(prow + dy) * 36 + (pcol + dx)];
                    #pragma unroll
                    for (int j = 0; j < 8; ++j)
                        accv[j] = fmaf(wr[j][dy * 3 + dx], iv, accv[j]);
                }
            unsigned d[4];
            #pragma unroll
            for (int jj = 0; jj < 4; ++jj) {
                unsigned short h0 = cvt_bf16_rne(fmaxf(accv[2 * jj + 0], 0.0f));
                unsigned short h1 = cvt_bf16_rne(fmaxf(accv[2 * jj + 1], 0.0f));
                d[jj] = (unsigned)h0 | ((unsigned)h1 << 16);
            }
            v = *(i32x4*)d;
        }
        lds4[px * 9 + o] = v;
    }
    __syncthreads();
    f32x4 acc[4][4];
    conv_mid_mainloop(lds4, apack_l, cb, acc, a, tid);
    conv_mid_store(acc, act_out, a, r0, c0, tid);
}

// ---------------------------------------------------------------------------
// Layer 4: 64 -> 1, no ReLU, fp32 out W_a[a][256][256].
// LDS-staged: halo read once (1.33x) instead of 9 global gathers per pixel.
__global__ __launch_bounds__(256, 3)
void conv_last_kernel(const unsigned short* __restrict__ act,
                      const float* __restrict__ cw4,
                      const float* __restrict__ cb4,
                      float* __restrict__ W_a) {
    __shared__ i32x4 lds4[340 * 9];
    int tid = threadIdx.x;
    int lin = blockIdx.x + (blockIdx.y << 3) + (blockIdx.z << 8);
    int wg = xcd_swz1024(lin);
    int a = wg >> 8;
    int r0 = ((wg >> 3) & 31) * 8, c0 = (wg & 7) * 32;
    conv_mid_stage(lds4, (const char*)act, a, r0, c0, tid);

    int lane = tid & 63, wv = tid >> 6;
    int o = lane & 7, pl = lane >> 3;
    float wr[8][9];
    #pragma unroll
    for (int j = 0; j < 8; ++j) {
        const float* wp = cw4 + ((size_t)a * 64 + o * 8 + j) * 9;
        #pragma unroll
        for (int t = 0; t < 9; ++t) wr[j][t] = wp[t];
    }
    float bias = cb4[a];
    __syncthreads();

    int c = wv * 8 + pl;            // column within tile, fixed per thread
    #pragma unroll 2
    for (int r = 0; r < 8; ++r) {   // row within tile
        float p = 0.0f;
        #pragma unroll
        for (int ty = 0; ty < 3; ++ty)
            #pragma unroll
            for (int tx = 0; tx < 3; ++tx) {
                i32x4 v = lds4[((r + ty) * 34 + (c + tx)) * 9 + o];
                const unsigned* dv = (const unsigned*)&v;
                #pragma unroll
                for (int j = 0; j < 8; ++j) {
                    unsigned d = dv[j >> 1];
                    unsigned short us = (j & 1) ? (unsigned short)(d >> 16)
                                                : (unsigned short)(d & 0xffffu);
                    p = fmaf(bf16_to_f32(us), wr[j][ty * 3 + tx], p);
                }
            }
        p += __shfl_xor(p, 1, 64);
        p += __shfl_xor(p, 2, 64);
        p += __shfl_xor(p, 4, 64);
        if (o == 0)
            W_a[(size_t)(a << 16) + ((r0 + r) << 8) + (c0 + c)] = p + bias;
    }
}

// ---------------------------------------------------------------------------
// Wy[b,x] = sum_h y[b,h] * W_a[actions[b], h, x].
// 1024 threads: 4 partial-threads per x column, 2-shuffle finish.
__global__ void wy_kernel(const float* __restrict__ yv,
                          const int* __restrict__ actions,
                          const float* __restrict__ W_a,
                          float* __restrict__ Wy) {
    int b = blockIdx.x, t = threadIdx.x;
    int x = t >> 2, hq = t & 3;
    int a = actions[b];
    const float* Wp = W_a + (size_t)a * 65536;
    const float* yb = yv + b * 256;
    float acc = 0.0f;
    #pragma unroll 8
    for (int i = 0; i < 64; ++i) {
        int h = i * 4 + hq;
        acc = fmaf(yb[h], Wp[(size_t)h * 256 + x], acc);
    }
    acc += __shfl_xor(acc, 1, 64);
    acc += __shfl_xor(acc, 2, 64);
    if (hq == 0) Wy[b * 256 + x] = acc;
}

// ---------------------------------------------------------------------------
// Logits: 16 lanes per row (lane = r*16+i), now 8 rows in flight per wave —
// two interleaved row-groups per iteration (8 independent float4 loads + two
// interleaved 4-step swizzle-shuffle reduces), masks prefetched at iteration
// top. grid (64, 32), 256 threads.
__global__ __launch_bounds__(256)
void logits_kernel(const float* __restrict__ xv,
                   const void* __restrict__ mask,
                   const int* __restrict__ flag,
                   const float* __restrict__ Wy,
                   float* __restrict__ out) {
    int tid = threadIdx.x, lane = tid & 63, w = tid >> 6;
    int i = lane & 15, r = lane >> 4;
    int b = blockIdx.y;
    int fl = *flag;
    float4 wyv[4];
    #pragma unroll
    for (int k = 0; k < 4; ++k)
        wyv[k] = *(const float4*)(Wy + b * 256 + k * 64 + i * 4);
    const float* xb = xv + (size_t)b * 4096 * 256;
    float ninf = -__builtin_inff();
    int base0 = blockIdx.x * 64 + w * 16;

    #pragma unroll 1
    for (int it = 0; it < 2; ++it) {
        int rowA = base0 + it * 8 + r;
        int rowB = rowA + 4;
        size_t miA = (size_t)b * 4096 + rowA;
        size_t miB = miA + 4;
        // mask prefetch (lane i==0 only), off the dot critical path
        bool mA = false, mB = false;
        if (i == 0) {
            if (fl & 2) {
                mA = ((const float*)mask)[miA] != 0.0f;
                mB = ((const float*)mask)[miB] != 0.0f;
            } else if (fl & 1) {
                mA = ((const unsigned char*)mask)[miA] != 0;
                mB = ((const unsigned char*)mask)[miB] != 0;
            } else {
                mA = ((const int*)mask)[miA] != 0;
                mB = ((const int*)mask)[miB] != 0;
            }
        }
        const float* rpA = xb + (size_t)rowA * 256 + i * 4;
        const float* rpB = xb + (size_t)rowB * 256 + i * 4;
        float4 xqA[4], xqB[4];
        #pragma unroll
        for (int k = 0; k < 4; ++k) xqA[k] = *(const float4*)(rpA + k * 64);
        #pragma unroll
        for (int k = 0; k < 4; ++k) xqB[k] = *(const float4*)(rpB + k * 64);
        float pA = 0.0f, pB = 0.0f;
        #pragma unroll
        for (int k = 0; k < 4; ++k) {
            pA = fmaf(xqA[k].x, wyv[k].x, pA);
            pA = fmaf(xqA[k].y, wyv[k].y, pA);
            pA = fmaf(xqA[k].z, wyv[k].z, pA);
            pA = fmaf(xqA[k].w, wyv[k].w, pA);
            pB = fmaf(xqB[k].x, wyv[k].x, pB);
            pB = fmaf(xqB[k].y, wyv[k].y, pB);
            pB = fmaf(xqB[k].z, wyv[k].z, pB);
            pB = fmaf(xqB[k].w, wyv[k].w, pB);
        }
        #pragma unroll
        for (int off = 8; off > 0; off >>= 1) {
            pA += __shfl_xor(pA, off, 64);
            pB += __shfl_xor(pB, off, 64);
        }
        if (i == 0) {
            out[miA] = mA ? ninf : pA;
            out[miB] = mB ? ninf : pB;
        }
    }
}

// ---------------------------------------------------------------------------
__global__ void softmax_kernel(float* __restrict__ out) {
    int b = blockIdx.x, tid = threadIdx.x;
    int lane = tid & 63, wid = tid >> 6;
    float* row = out + (size_t)b * 4096;
    float v[4];
    float m = -__builtin_inff();
    #pragma unroll
    for (int i = 0; i < 4; ++i) { v[i] = row[tid + i * 1024]; m = fmaxf(m, v[i]); }
    #pragma unroll
    for (int off = 32; off > 0; off >>= 1) m = fmaxf(m, __shfl_xor(m, off, 64));
    __shared__ float redm[16];
    __shared__ float reds[16];
    if (lane == 0) redm[wid] = m;
    __syncthreads();
    float M = redm[0];
    #pragma unroll
    for (int j = 1; j < 16; ++j) M = fmaxf(M, redm[j]);
    float s = 0.0f;
    #pragma unroll
    for (int i = 0; i < 4; ++i) { v[i] = expf(v[i] - M); s += v[i]; }
    #pragma unroll
    for (int off = 32; off > 0; off >>= 1) s += __shfl_xor(s, off, 64);
    if (lane == 0) reds[wid] = s;
    __syncthreads();
    float S = 0.0f;
    #pragma unroll
    for (int j = 0; j < 16; ++j) S += reds[j];
    float inv = 1.0f / S;
    #pragma unroll
    for (int i = 0; i < 4; ++i) row[tid + i * 1024] = v[i] * inv;
}

// ---------------------------------------------------------------------------
extern "C" void kernel_launch(void* const* d_in, const int* in_sizes, int n_in,
                              void* d_out, int out_size, void* d_ws, size_t ws_size,
                              hipStream_t stream) {
    const float* xv      = (const float*)d_in[0];
    const float* yv      = (const float*)d_in[1];
    const void*  xmask   = d_in[2];
    const int*   actions = (const int*)d_in[3];
    const float* weight  = (const float*)d_in[4];
    const float* cw0 = (const float*)d_in[5];
    const float* cb0 = (const float*)d_in[6];
    const float* cw1 = (const float*)d_in[7];
    const float* cb1 = (const float*)d_in[8];
    const float* cw2 = (const float*)d_in[9];
    const float* cb2 = (const float*)d_in[10];
    const float* cw3 = (const float*)d_in[11];
    const float* cb3 = (const float*)d_in[12];
    const float* cw4 = (const float*)d_in[13];
    const float* cb4 = (const float*)d_in[14];
    float* out = (float*)d_out;

    char* ws = (char*)d_ws;
    unsigned short* bufA = (unsigned short*)ws;                    // 33554432 B
    unsigned short* bufB = (unsigned short*)(ws + 33554432);       // 33554432 B
    char*  apack = ws + 67108864;                                  // 3 x 294912 B
    float* W_a   = (float*)(ws + 67993600);                        // 1048576 B
    float* Wy    = (float*)(ws + 69042176);                        // 32768 B
    int*   flag  = (int*)(ws + 69074944);                          // 4 B

    // Packing launch: apack L1-3 + clear flag (detect runs inside fused0).
    apack_all_kernel<<<dim3(9, 4, 3), 512, 0, stream>>>(cw1, cw2, cw3, apack, flag);

    // L0+L1 fused (+ detect in z==4 slice) -> bufA; L2 -> bufB; L3 -> bufA.
    conv_mid_fused0<<<dim3(8, 32, 5), 256, 0, stream>>>(weight, cw0, cb0, apack, cb1, bufA,
                                                        (const unsigned int*)xmask, flag);
    conv_mid_mfma<<<dim3(8, 32, 4), 256, 0, stream>>>(bufA, apack + 294912, cb2, bufB);
    conv_mid_mfma<<<dim3(8, 32, 4), 256, 0, stream>>>(bufB, apack + 589824, cb3, bufA);
    conv_last_kernel<<<dim3(8, 32, 4), 256, 0, stream>>>(bufA, cw4, cb4, W_a);

    wy_kernel<<<32, 1024, 0, stream>>>(yv, actions, W_a, Wy);
    logits_kernel<<<dim3(64, 32), 256, 0, stream>>>(xv, xmask, flag, Wy, out);
    softmax_kernel<<<32, 1024, 0, stream>>>(out);
}

// Round 8
// 327.538 us; speedup vs baseline: 1.0439x; 1.0439x over previous
//
#include <hip/hip_runtime.h>
#include <cstdint>
#include <cstddef>

typedef __attribute__((ext_vector_type(8))) short bf16x8;
typedef __attribute__((ext_vector_type(4))) float f32x4;
typedef __attribute__((ext_vector_type(4))) int i32x4;

__device__ inline unsigned short cvt_bf16_rne(float f) {
    unsigned u = __builtin_bit_cast(unsigned, f);
    u = (u + 0x7FFFu + ((u >> 16) & 1u)) >> 16;
    return (unsigned short)u;
}
__device__ inline float bf16_to_f32(unsigned short s) {
    return __builtin_bit_cast(float, (unsigned)s << 16);
}

// XCD-aware bijective swizzle for 1024-block conv grids (1024 % 8 == 0):
// hardware round-robins dispatch index lin across XCDs; remap so each XCD
// owns a contiguous 128-tile chunk (one action's half -> its apack slice and
// halo rows stay in that XCD's private L2).
__device__ __forceinline__ int xcd_swz1024(int lin) {
    return (lin & 7) * 128 + (lin >> 3);
}

// ---------------------------------------------------------------------------
// Pack mid-layer weights (layers 1..3) into MFMA A-fragment lane order (bf16).
// grid dim3(9, 4, 3) [tap, action, layer], 512 threads.
// Block (0,0,0) also clears the mask-format flag (detect runs in a LATER
// kernel -> stream order guarantees the clear lands first).
__global__ void apack_all_kernel(const float* __restrict__ cw1,
                                 const float* __restrict__ cw2,
                                 const float* __restrict__ cw3,
                                 char* __restrict__ apack,
                                 int* __restrict__ flag) {
    int t = threadIdx.x;
    int tap = blockIdx.x, a = blockIdx.y, lz = blockIdx.z;
    if (tap == 0 && a == 0 && lz == 0 && t == 0) *flag = 0;
    const float* cw = (lz == 0) ? cw1 : (lz == 1 ? cw2 : cw3);
    char* outp = apack + (size_t)lz * 294912;
    int ks = t >> 8, mf = (t >> 6) & 3, lane = t & 63;
    int n = lane & 15, q = lane >> 4;
    int co = mf * 16 + n;
    int ci0 = ks * 32 + q * 8;
    unsigned d[4];
    #pragma unroll
    for (int jj = 0; jj < 4; ++jj) {
        unsigned short h0 = cvt_bf16_rne(cw[((size_t)(a * 64 + co) * 64 + ci0 + 2 * jj + 0) * 9 + tap]);
        unsigned short h1 = cvt_bf16_rne(cw[((size_t)(a * 64 + co) * 64 + ci0 + 2 * jj + 1) * 9 + tap]);
        d[jj] = (unsigned)h0 | ((unsigned)h1 << 16);
    }
    *(i32x4*)(outp + ((((size_t)(a * 9 + tap) * 2 + ks) * 4 + mf) * 1024 + lane * 16)) =
        *(i32x4*)d;
}

// ---------------------------------------------------------------------------
// Shared MFMA main loop for the mid layers: consumes the staged 10x34 halo
// tile in lds4, runs the 64->64 implicit GEMM into acc (bias pre-loaded).
__device__ __forceinline__ void conv_mid_mainloop(const i32x4* lds4,
                                                  const char* __restrict__ apack_l,
                                                  const float* __restrict__ cb,
                                                  f32x4 acc[4][4],
                                                  int a, int tid) {
    int lane = tid & 63, wv = tid >> 6;
    int n = lane & 15, q = lane >> 4;

    #pragma unroll
    for (int mf = 0; mf < 4; ++mf) {
        f32x4 bb = *(const f32x4*)(cb + a * 64 + mf * 16 + q * 4);
        #pragma unroll
        for (int nf = 0; nf < 4; ++nf) acc[mf][nf] = bb;
    }

    int base_nf[4];
    #pragma unroll
    for (int nf = 0; nf < 4; ++nf) {
        int orl = wv * 2 + (nf >> 1);
        int ocl = ((nf & 1) << 4) + n;
        base_nf[nf] = (orl * 34 + ocl) * 9 + q;  // i32x4 index at ty=tx=0,ks=0
    }
    const char* ap = apack_l + (size_t)a * 9 * 8192 + lane * 16;

    #pragma unroll
    for (int tap = 0; tap < 9; ++tap) {
        const int ty = tap / 3, tx = tap - ty * 3;
        const int toff = (ty * 34 + tx) * 9;
        #pragma unroll
        for (int ks = 0; ks < 2; ++ks) {
            bf16x8 Af[4], Bf[4];
            #pragma unroll
            for (int mf = 0; mf < 4; ++mf)
                Af[mf] = __builtin_bit_cast(bf16x8,
                    *(const i32x4*)(ap + (((tap * 2 + ks) * 4 + mf) << 10)));
            #pragma unroll
            for (int nf = 0; nf < 4; ++nf)
                Bf[nf] = __builtin_bit_cast(bf16x8, lds4[base_nf[nf] + toff + ks * 4]);
            #pragma unroll
            for (int mf = 0; mf < 4; ++mf)
                #pragma unroll
                for (int nf = 0; nf < 4; ++nf)
                    acc[mf][nf] = __builtin_amdgcn_mfma_f32_16x16x32_bf16(
                        Af[mf], Bf[nf], acc[mf][nf], 0, 0, 0);
        }
    }
}

// Standard epilogue: ReLU + bf16 pack + store act tile.
__device__ __forceinline__ void conv_mid_store(f32x4 acc[4][4],
                                               unsigned short* __restrict__ act_out,
                                               int a, int r0, int c0, int tid) {
    int lane = tid & 63, wv = tid >> 6;
    int n = lane & 15, q = lane >> 4;
    #pragma unroll
    for (int nf = 0; nf < 4; ++nf) {
        int grow = r0 + wv * 2 + (nf >> 1);
        int gcol = c0 + ((nf & 1) << 4) + n;
        char* ob = (char*)act_out + (((size_t)(a << 16) + (grow << 8) + gcol) << 7) + q * 8;
        #pragma unroll
        for (int mf = 0; mf < 4; ++mf) {
            f32x4 v = acc[mf][nf];
            unsigned d0 = (unsigned)cvt_bf16_rne(fmaxf(v.x, 0.0f))
                        | ((unsigned)cvt_bf16_rne(fmaxf(v.y, 0.0f)) << 16);
            unsigned d1 = (unsigned)cvt_bf16_rne(fmaxf(v.z, 0.0f))
                        | ((unsigned)cvt_bf16_rne(fmaxf(v.w, 0.0f)) << 16);
            uint2 st; st.x = d0; st.y = d1;
            *(uint2*)(ob + mf * 32) = st;
        }
    }
}

// Halo staging from a bf16 act buffer.
__device__ __forceinline__ void conv_mid_stage(i32x4* lds4,
                                               const char* __restrict__ actb,
                                               int a, int r0, int c0, int tid) {
    for (int s = tid; s < 2720; s += 256) {
        int px = s >> 3, o = s & 7;
        int prow = px / 34, pcol = px - prow * 34;
        int grow = r0 - 1 + prow, gcol = c0 - 1 + pcol;
        i32x4 v = {0, 0, 0, 0};
        if ((unsigned)grow < 256u && (unsigned)gcol < 256u)
            v = *(const i32x4*)(actb + (((size_t)(a << 16) + (grow << 8) + gcol) << 7) + (o << 4));
        lds4[px * 9 + o] = v;
    }
}

// ---------------------------------------------------------------------------
// Mid layers 2,3: stage bf16 act tile from global, MFMA, store act tile.
// grid dim3(8, 32, 4), 256 threads, XCD-swizzled.
__global__ __launch_bounds__(256, 3)
void conv_mid_mfma(const unsigned short* __restrict__ act_in,
                   const char* __restrict__ apack_l,
                   const float* __restrict__ cb,
                   unsigned short* __restrict__ act_out) {
    __shared__ i32x4 lds4[340 * 9];
    int tid = threadIdx.x;
    int lin = blockIdx.x + (blockIdx.y << 3) + (blockIdx.z << 8);
    int wg = xcd_swz1024(lin);
    int a = wg >> 8;
    int r0 = ((wg >> 3) & 31) * 8, c0 = (wg & 7) * 32;
    conv_mid_stage(lds4, (const char*)act_in, a, r0, c0, tid);
    __syncthreads();
    f32x4 acc[4][4];
    conv_mid_mainloop(lds4, apack_l, cb, acc, a, tid);
    conv_mid_store(acc, act_out, a, r0, c0, tid);
}

// ---------------------------------------------------------------------------
// Layer 1 with layer 0 fused (z<4), plus the mask-format detect folded into
// the spare z==4 slice (flag was cleared by the preceding apack launch).
// grid dim3(8, 32, 5), 256 threads.
__global__ __launch_bounds__(256, 3)
void conv_mid_fused0(const float* __restrict__ img,
                     const float* __restrict__ cw0,
                     const float* __restrict__ cb0,
                     const char* __restrict__ apack_l,
                     const float* __restrict__ cb,
                     unsigned short* __restrict__ act_out,
                     const unsigned int* __restrict__ mask_u32,
                     int* __restrict__ flag) {
    __shared__ i32x4 lds4[340 * 9];
    __shared__ float img_s[12 * 36];
    int tid = threadIdx.x;

    if (blockIdx.z == 4) {
        // detect x_mask storage: 0 = int32 {0,1}, 1 = bytes, 2 = float32
        if (blockIdx.y < 4) {
            int i = ((blockIdx.y * 8 + blockIdx.x) * 256 + tid);
            int f = 0;
            #pragma unroll
            for (int k = 0; k < 4; ++k) {
                unsigned int v = mask_u32[i * 4 + k];
                if (v == 0x3F800000u) f |= 2;
                else if (v > 1u) f |= 1;
            }
            if (f) atomicOr(flag, f);
        }
        return;
    }

    int lin = blockIdx.x + (blockIdx.y << 3) + (blockIdx.z << 8);
    int wg = xcd_swz1024(lin);
    int a = wg >> 8;
    int r0 = ((wg >> 3) & 31) * 8, c0 = (wg & 7) * 32;

    for (int s = tid; s < 432; s += 256) {
        int ir = s / 36, ic = s - ir * 36;
        int gr = r0 - 2 + ir, gc = c0 - 2 + ic;
        img_s[s] = ((unsigned)gr < 256u && (unsigned)gc < 256u) ? img[gr * 256 + gc] : 0.0f;
    }
    __syncthreads();

    int o = tid & 7;
    float wr[8][9], br[8];
    #pragma unroll
    for (int j = 0; j < 8; ++j) {
        const float* wp = cw0 + ((size_t)a * 64 + o * 8 + j) * 9;
        #pragma unroll
        for (int t = 0; t < 9; ++t) wr[j][t] = wp[t];
        br[j] = cb0[a * 64 + o * 8 + j];
    }

    for (int s = tid; s < 2720; s += 256) {
        int px = s >> 3;
        int prow = px / 34, pcol = px - prow * 34;
        int grow = r0 - 1 + prow, gcol = c0 - 1 + pcol;
        i32x4 v = {0, 0, 0, 0};
        if ((unsigned)grow < 256u && (unsigned)gcol < 256u) {
            float accv[8];
            #pragma unroll
            for (int j = 0; j < 8; ++j) accv[j] = br[j];
            #pragma unroll
            for (int dy = 0; dy < 3; ++dy)
                #pragma unroll
                for (int dx = 0; dx < 3; ++dx) {
                    float iv = img_s[(prow + dy) * 36 + (pcol + dx)];
                    #pragma unroll
                    for (int j = 0; j < 8; ++j)
                        accv[j] = fmaf(wr[j][dy * 3 + dx], iv, accv[j]);
                }
            unsigned d[4];
            #pragma unroll
            for (int jj = 0; jj < 4; ++jj) {
                unsigned short h0 = cvt_bf16_rne(fmaxf(accv[2 * jj + 0], 0.0f));
                unsigned short h1 = cvt_bf16_rne(fmaxf(accv[2 * jj + 1], 0.0f));
                d[jj] = (unsigned)h0 | ((unsigned)h1 << 16);
            }
            v = *(i32x4*)d;
        }
        lds4[px * 9 + o] = v;
    }
    __syncthreads();
    f32x4 acc[4][4];
    conv_mid_mainloop(lds4, apack_l, cb, acc, a, tid);
    conv_mid_store(acc, act_out, a, r0, c0, tid);
}

// ---------------------------------------------------------------------------
// Layer 4: 64 -> 1, no ReLU, fp32 out W_a[a][256][256].
// LDS-staged: halo read once (1.33x) instead of 9 global gathers per pixel.
__global__ __launch_bounds__(256, 3)
void conv_last_kernel(const unsigned short* __restrict__ act,
                      const float* __restrict__ cw4,
                      const float* __restrict__ cb4,
                      float* __restrict__ W_a) {
    __shared__ i32x4 lds4[340 * 9];
    int tid = threadIdx.x;
    int lin = blockIdx.x + (blockIdx.y << 3) + (blockIdx.z << 8);
    int wg = xcd_swz1024(lin);
    int a = wg >> 8;
    int r0 = ((wg >> 3) & 31) * 8, c0 = (wg & 7) * 32;
    conv_mid_stage(lds4, (const char*)act, a, r0, c0, tid);

    int lane = tid & 63, wv = tid >> 6;
    int o = lane & 7, pl = lane >> 3;
    float wr[8][9];
    #pragma unroll
    for (int j = 0; j < 8; ++j) {
        const float* wp = cw4 + ((size_t)a * 64 + o * 8 + j) * 9;
        #pragma unroll
        for (int t = 0; t < 9; ++t) wr[j][t] = wp[t];
    }
    float bias = cb4[a];
    __syncthreads();

    int c = wv * 8 + pl;            // column within tile, fixed per thread
    #pragma unroll 2
    for (int r = 0; r < 8; ++r) {   // row within tile
        float p = 0.0f;
        #pragma unroll
        for (int ty = 0; ty < 3; ++ty)
            #pragma unroll
            for (int tx = 0; tx < 3; ++tx) {
                i32x4 v = lds4[((r + ty) * 34 + (c + tx)) * 9 + o];
                const unsigned* dv = (const unsigned*)&v;
                #pragma unroll
                for (int j = 0; j < 8; ++j) {
                    unsigned d = dv[j >> 1];
                    unsigned short us = (j & 1) ? (unsigned short)(d >> 16)
                                                : (unsigned short)(d & 0xffffu);
                    p = fmaf(bf16_to_f32(us), wr[j][ty * 3 + tx], p);
                }
            }
        p += __shfl_xor(p, 1, 64);
        p += __shfl_xor(p, 2, 64);
        p += __shfl_xor(p, 4, 64);
        if (o == 0)
            W_a[(size_t)(a << 16) + ((r0 + r) << 8) + (c0 + c)] = p + bias;
    }
}

// ---------------------------------------------------------------------------
// Wy[b,x] = sum_h y[b,h] * W_a[actions[b], h, x].
// 1024 threads: 4 partial-threads per x column, 2-shuffle finish.
__global__ void wy_kernel(const float* __restrict__ yv,
                          const int* __restrict__ actions,
                          const float* __restrict__ W_a,
                          float* __restrict__ Wy) {
    int b = blockIdx.x, t = threadIdx.x;
    int x = t >> 2, hq = t & 3;
    int a = actions[b];
    const float* Wp = W_a + (size_t)a * 65536;
    const float* yb = yv + b * 256;
    float acc = 0.0f;
    #pragma unroll 8
    for (int i = 0; i < 64; ++i) {
        int h = i * 4 + hq;
        acc = fmaf(yb[h], Wp[(size_t)h * 256 + x], acc);
    }
    acc += __shfl_xor(acc, 1, 64);
    acc += __shfl_xor(acc, 2, 64);
    if (hq == 0) Wy[b * 256 + x] = acc;
}

// ---------------------------------------------------------------------------
// Logits: 16 lanes per row, 8 rows in flight per wave, with MASK-GATED x
// loads: ~50% of rows are masked to -inf, so the mask is read FIRST (one
// broadcast load per 16-lane row-group) and the 1KB x-row read is skipped
// (exec-masked off) for masked rows — halving the dominant memory stream.
// Shuffle reduces run unconditionally (all lanes participate; masked groups
// reduce a dead zero). grid (64, 32), 256 threads.
__global__ __launch_bounds__(256)
void logits_kernel(const float* __restrict__ xv,
                   const void* __restrict__ mask,
                   const int* __restrict__ flag,
                   const float* __restrict__ Wy,
                   float* __restrict__ out) {
    int tid = threadIdx.x, lane = tid & 63, w = tid >> 6;
    int i = lane & 15, r = lane >> 4;
    int b = blockIdx.y;
    int fl = *flag;
    const float* xb = xv + (size_t)b * 4096 * 256;
    float ninf = -__builtin_inff();
    int base0 = blockIdx.x * 64 + w * 16;
    size_t mb = (size_t)b * 4096;

    // All 4 row-group masks up front (same addr across 16-lane group ->
    // broadcast); independent of the Wy load below.
    int rw0 = base0 + r, rw1 = base0 + r + 4,
        rw2 = base0 + r + 8, rw3 = base0 + r + 12;
    bool m0, m1, m2, m3;
    if (fl & 2) {
        const float* mp = (const float*)mask + mb;
        m0 = mp[rw0] != 0.0f; m1 = mp[rw1] != 0.0f;
        m2 = mp[rw2] != 0.0f; m3 = mp[rw3] != 0.0f;
    } else if (fl & 1) {
        const unsigned char* mp = (const unsigned char*)mask + mb;
        m0 = mp[rw0] != 0; m1 = mp[rw1] != 0;
        m2 = mp[rw2] != 0; m3 = mp[rw3] != 0;
    } else {
        const int* mp = (const int*)mask + mb;
        m0 = mp[rw0] != 0; m1 = mp[rw1] != 0;
        m2 = mp[rw2] != 0; m3 = mp[rw3] != 0;
    }

    float4 wyv[4];
    #pragma unroll
    for (int k = 0; k < 4; ++k)
        wyv[k] = *(const float4*)(Wy + b * 256 + k * 64 + i * 4);

    int rows[4] = {rw0, rw1, rw2, rw3};
    bool ms[4] = {m0, m1, m2, m3};

    #pragma unroll 1
    for (int it = 0; it < 2; ++it) {
        int rowA = rows[it * 2 + 0], rowB = rows[it * 2 + 1];
        bool mA = ms[it * 2 + 0],  mB = ms[it * 2 + 1];
        float pA = 0.0f, pB = 0.0f;
        if (!mA) {
            const float* rp = xb + (size_t)rowA * 256 + i * 4;
            float4 xq[4];
            #pragma unroll
            for (int k = 0; k < 4; ++k) xq[k] = *(const float4*)(rp + k * 64);
            #pragma unroll
            for (int k = 0; k < 4; ++k) {
                pA = fmaf(xq[k].x, wyv[k].x, pA);
                pA = fmaf(xq[k].y, wyv[k].y, pA);
                pA = fmaf(xq[k].z, wyv[k].z, pA);
                pA = fmaf(xq[k].w, wyv[k].w, pA);
            }
        }
        if (!mB) {
            const float* rp = xb + (size_t)rowB * 256 + i * 4;
            float4 xq[4];
            #pragma unroll
            for (int k = 0; k < 4; ++k) xq[k] = *(const float4*)(rp + k * 64);
            #pragma unroll
            for (int k = 0; k < 4; ++k) {
                pB = fmaf(xq[k].x, wyv[k].x, pB);
                pB = fmaf(xq[k].y, wyv[k].y, pB);
                pB = fmaf(xq[k].z, wyv[k].z, pB);
                pB = fmaf(xq[k].w, wyv[k].w, pB);
            }
        }
        #pragma unroll
        for (int off = 8; off > 0; off >>= 1) {
            pA += __shfl_xor(pA, off, 64);
            pB += __shfl_xor(pB, off, 64);
        }
        if (i == 0) {
            out[mb + rowA] = mA ? ninf : pA;
            out[mb + rowB] = mB ? ninf : pB;
        }
    }
}

// ---------------------------------------------------------------------------
__global__ void softmax_kernel(float* __restrict__ out) {
    int b = blockIdx.x, tid = threadIdx.x;
    int lane = tid & 63, wid = tid >> 6;
    float* row = out + (size_t)b * 4096;
    float v[4];
    float m = -__builtin_inff();
    #pragma unroll
    for (int i = 0; i < 4; ++i) { v[i] = row[tid + i * 1024]; m = fmaxf(m, v[i]); }
    #pragma unroll
    for (int off = 32; off > 0; off >>= 1) m = fmaxf(m, __shfl_xor(m, off, 64));
    __shared__ float redm[16];
    __shared__ float reds[16];
    if (lane == 0) redm[wid] = m;
    __syncthreads();
    float M = redm[0];
    #pragma unroll
    for (int j = 1; j < 16; ++j) M = fmaxf(M, redm[j]);
    float s = 0.0f;
    #pragma unroll
    for (int i = 0; i < 4; ++i) { v[i] = expf(v[i] - M); s += v[i]; }
    #pragma unroll
    for (int off = 32; off > 0; off >>= 1) s += __shfl_xor(s, off, 64);
    if (lane == 0) reds[wid] = s;
    __syncthreads();
    float S = 0.0f;
    #pragma unroll
    for (int j = 0; j < 16; ++j) S += reds[j];
    float inv = 1.0f / S;
    #pragma unroll
    for (int i = 0; i < 4; ++i) row[tid + i * 1024] = v[i] * inv;
}

// ---------------------------------------------------------------------------
extern "C" void kernel_launch(void* const* d_in, const int* in_sizes, int n_in,
                              void* d_out, int out_size, void* d_ws, size_t ws_size,
                              hipStream_t stream) {
    const float* xv      = (const float*)d_in[0];
    const float* yv      = (const float*)d_in[1];
    const void*  xmask   = d_in[2];
    const int*   actions = (const int*)d_in[3];
    const float* weight  = (const float*)d_in[4];
    const float* cw0 = (const float*)d_in[5];
    const float* cb0 = (const float*)d_in[6];
    const float* cw1 = (const float*)d_in[7];
    const float* cb1 = (const float*)d_in[8];
    const float* cw2 = (const float*)d_in[9];
    const float* cb2 = (const float*)d_in[10];
    const float* cw3 = (const float*)d_in[11];
    const float* cb3 = (const float*)d_in[12];
    const float* cw4 = (const float*)d_in[13];
    const float* cb4 = (const float*)d_in[14];
    float* out = (float*)d_out;

    char* ws = (char*)d_ws;
    unsigned short* bufA = (unsigned short*)ws;                    // 33554432 B
    unsigned short* bufB = (unsigned short*)(ws + 33554432);       // 33554432 B
    char*  apack = ws + 67108864;                                  // 3 x 294912 B
    float* W_a   = (float*)(ws + 67993600);                        // 1048576 B
    float* Wy    = (float*)(ws + 69042176);                        // 32768 B
    int*   flag  = (int*)(ws + 69074944);                          // 4 B

    // Packing launch: apack L1-3 + clear flag (detect runs inside fused0).
    apack_all_kernel<<<dim3(9, 4, 3), 512, 0, stream>>>(cw1, cw2, cw3, apack, flag);

    // L0+L1 fused (+ detect in z==4 slice) -> bufA; L2 -> bufB; L3 -> bufA.
    conv_mid_fused0<<<dim3(8, 32, 5), 256, 0, stream>>>(weight, cw0, cb0, apack, cb1, bufA,
                                                        (const unsigned int*)xmask, flag);
    conv_mid_mfma<<<dim3(8, 32, 4), 256, 0, stream>>>(bufA, apack + 294912, cb2, bufB);
    conv_mid_mfma<<<dim3(8, 32, 4), 256, 0, stream>>>(bufB, apack + 589824, cb3, bufA);
    conv_last_kernel<<<dim3(8, 32, 4), 256, 0, stream>>>(bufA, cw4, cb4, W_a);

    wy_kernel<<<32, 1024, 0, stream>>>(yv, actions, W_a, Wy);
    logits_kernel<<<dim3(64, 32), 256, 0, stream>>>(xv, xmask, flag, Wy, out);
    softmax_kernel<<<32, 1024, 0, stream>>>(out);
}